// Round 2
// baseline (225.935 us; speedup 1.0000x reference)
//
#include <hip/hip_runtime.h>

// Haar inverse DWT: out[b,c,2y+dy,2x+dx] from 4 subbands, each (8,64,256,256) f32.
// Pure streaming (1.074 GB once-touched), HBM-bound. Round 2 change: non-temporal
// loads/stores (nt flag) — data has zero reuse, so mark lines evict-first to cut
// L2/Infinity-Cache churn from streaming 1 GiB through 32 MiB / 256 MiB caches.
//
// Indexing: flatten inputs to rows of W=256 (R = 8*64*256 rows). Input row r ->
// output rows 2r / 2r+1; the output row-pair base is exactly r*1024
// (plane*512*512 + 2y*512 == (plane*256+y)*1024). Each thread consumes one
// float4 per subband and writes 2 float4 to the top row (tl,tr interleaved)
// and 2 to the bottom row (bl,br).

using f32x4 = __attribute__((ext_vector_type(4))) float;

__global__ __launch_bounds__(256) void HaarIDWT_kernel(
    const float* __restrict__ ll, const float* __restrict__ lh,
    const float* __restrict__ hl, const float* __restrict__ hh,
    float* __restrict__ out, int nvec)
{
    const int v = blockIdx.x * blockDim.x + threadIdx.x;
    if (v >= nvec) return;

    const f32x4 a = __builtin_nontemporal_load(reinterpret_cast<const f32x4*>(ll) + v);
    const f32x4 b = __builtin_nontemporal_load(reinterpret_cast<const f32x4*>(lh) + v);
    const f32x4 c = __builtin_nontemporal_load(reinterpret_cast<const f32x4*>(hl) + v);
    const f32x4 d = __builtin_nontemporal_load(reinterpret_cast<const f32x4*>(hh) + v);

    f32x4 top0, top1, bot0, bot1;
    // input col j -> output cols 2j (t/b-left), 2j+1 (t/b-right)
    top0[0] = 0.5f * (a[0] - b[0] - c[0] + d[0]);
    top0[1] = 0.5f * (a[0] - b[0] + c[0] - d[0]);
    top0[2] = 0.5f * (a[1] - b[1] - c[1] + d[1]);
    top0[3] = 0.5f * (a[1] - b[1] + c[1] - d[1]);
    top1[0] = 0.5f * (a[2] - b[2] - c[2] + d[2]);
    top1[1] = 0.5f * (a[2] - b[2] + c[2] - d[2]);
    top1[2] = 0.5f * (a[3] - b[3] - c[3] + d[3]);
    top1[3] = 0.5f * (a[3] - b[3] + c[3] - d[3]);

    bot0[0] = 0.5f * (a[0] + b[0] - c[0] - d[0]);
    bot0[1] = 0.5f * (a[0] + b[0] + c[0] + d[0]);
    bot0[2] = 0.5f * (a[1] + b[1] - c[1] - d[1]);
    bot0[3] = 0.5f * (a[1] + b[1] + c[1] + d[1]);
    bot1[0] = 0.5f * (a[2] + b[2] - c[2] - d[2]);
    bot1[1] = 0.5f * (a[2] + b[2] + c[2] + d[2]);
    bot1[2] = 0.5f * (a[3] + b[3] - c[3] - d[3]);
    bot1[3] = 0.5f * (a[3] + b[3] + c[3] + d[3]);

    const int row  = v >> 6;                 // v / (256/4)
    const int xv   = v & 63;                 // float4 index within the row
    const int otop = row * 1024 + xv * 8;    // output row 2*row
    const int obot = otop + 512;             // output row 2*row+1

    f32x4* ot = reinterpret_cast<f32x4*>(out + otop);
    f32x4* ob = reinterpret_cast<f32x4*>(out + obot);
    __builtin_nontemporal_store(top0, ot);
    __builtin_nontemporal_store(top1, ot + 1);
    __builtin_nontemporal_store(bot0, ob);
    __builtin_nontemporal_store(bot1, ob + 1);
}

extern "C" void kernel_launch(void* const* d_in, const int* in_sizes, int n_in,
                              void* d_out, int out_size, void* d_ws, size_t ws_size,
                              hipStream_t stream) {
    const float* ll = (const float*)d_in[0];
    const float* lh = (const float*)d_in[1];
    const float* hl = (const float*)d_in[2];
    const float* hh = (const float*)d_in[3];
    float* out = (float*)d_out;

    const int n    = in_sizes[0];        // 8*64*256*256 = 33,554,432
    const int nvec = n / 4;              // 8,388,608 float4's per subband

    const int block = 256;
    const int grid  = (nvec + block - 1) / block;   // 32768
    HaarIDWT_kernel<<<grid, block, 0, stream>>>(ll, lh, hl, hh, out, nvec);
}

// Round 3
// 187.153 us; speedup vs baseline: 1.2072x; 1.2072x over previous
//
#include <hip/hip_runtime.h>

// Haar inverse DWT: out[b,c,2y+dy,2x+dx] from 4 subbands, each (8,64,256,256) f32.
// Pure streaming (1.074 GB once-touched), HBM-bound.
//
// Round 3: revert nt (regressed −16%); make ALL stores unit-stride across lanes.
// Mapping: one wave (64 lanes) per input row (256 floats = 128 float2).
//   lane l loads float2 idx j1=l and j2=64+l of the row from each subband (8 B/lane,
//   wave covers a contiguous 512 B segment per load instruction).
//   Input float2 j (cols 2j,2j+1) -> output float4 j of the top row and float4 j of
//   the bottom row. Output row pair base = row*1024 floats = float4 idx row*256:
//     top  = float4 [row*256      , row*256+128)
//     bot  = float4 [row*256 + 128, row*256+256)
//   So stores: lane l -> idx row*256 + {l, 64+l, 128+l, 192+l} — all four store
//   instructions are lane-contiguous 16 B/lane = 1 KB/instr (full cachelines),
//   no cross-lane exchange needed.

using f32x2 = __attribute__((ext_vector_type(2))) float;
using f32x4 = __attribute__((ext_vector_type(4))) float;

__device__ __forceinline__ void haar_pair(const f32x2 a, const f32x2 b,
                                          const f32x2 c, const f32x2 d,
                                          f32x4& top, f32x4& bot)
{
    top[0] = 0.5f * (a[0] - b[0] - c[0] + d[0]);  // tl
    top[1] = 0.5f * (a[0] - b[0] + c[0] - d[0]);  // tr
    top[2] = 0.5f * (a[1] - b[1] - c[1] + d[1]);
    top[3] = 0.5f * (a[1] - b[1] + c[1] - d[1]);
    bot[0] = 0.5f * (a[0] + b[0] - c[0] - d[0]);  // bl
    bot[1] = 0.5f * (a[0] + b[0] + c[0] + d[0]);  // br
    bot[2] = 0.5f * (a[1] + b[1] - c[1] - d[1]);
    bot[3] = 0.5f * (a[1] + b[1] + c[1] + d[1]);
}

__global__ __launch_bounds__(256) void HaarIDWT_kernel(
    const float* __restrict__ ll, const float* __restrict__ lh,
    const float* __restrict__ hl, const float* __restrict__ hh,
    float* __restrict__ out, int nthreads)
{
    const int t = blockIdx.x * blockDim.x + threadIdx.x;
    if (t >= nthreads) return;

    const int w = t >> 6;        // wave id == input row index (8*64*256 rows)
    const int l = t & 63;        // lane

    const f32x2* ll2 = reinterpret_cast<const f32x2*>(ll);
    const f32x2* lh2 = reinterpret_cast<const f32x2*>(lh);
    const f32x2* hl2 = reinterpret_cast<const f32x2*>(hl);
    const f32x2* hh2 = reinterpret_cast<const f32x2*>(hh);

    const int g1 = w * 128 + l;      // float2 index, first half of the row
    const int g2 = g1 + 64;          // second half

    const f32x2 a1 = ll2[g1], a2 = ll2[g2];
    const f32x2 b1 = lh2[g1], b2 = lh2[g2];
    const f32x2 c1 = hl2[g1], c2 = hl2[g2];
    const f32x2 d1 = hh2[g1], d2 = hh2[g2];

    f32x4 top1, bot1, top2, bot2;
    haar_pair(a1, b1, c1, d1, top1, bot1);
    haar_pair(a2, b2, c2, d2, top2, bot2);

    f32x4* out4 = reinterpret_cast<f32x4*>(out);
    const int base = w * 256;        // float4 index of this row-pair's output
    out4[base +       l] = top1;     // top row, first half
    out4[base +  64 + l] = top2;     // top row, second half
    out4[base + 128 + l] = bot1;     // bottom row, first half
    out4[base + 192 + l] = bot2;     // bottom row, second half
}

extern "C" void kernel_launch(void* const* d_in, const int* in_sizes, int n_in,
                              void* d_out, int out_size, void* d_ws, size_t ws_size,
                              hipStream_t stream) {
    const float* ll = (const float*)d_in[0];
    const float* lh = (const float*)d_in[1];
    const float* hl = (const float*)d_in[2];
    const float* hh = (const float*)d_in[3];
    float* out = (float*)d_out;

    const int n        = in_sizes[0];   // 8*64*256*256 = 33,554,432
    const int nthreads = n / 4;         // one thread per 2 float2 per subband

    const int block = 256;
    const int grid  = (nthreads + block - 1) / block;   // 32768
    HaarIDWT_kernel<<<grid, block, 0, stream>>>(ll, lh, hl, hh, out, nthreads);
}